// Round 1
// baseline (255.751 us; speedup 1.0000x reference)
//
#include <hip/hip_runtime.h>

// self_attention: x(4,2048,1024) fp32; Q=xWq^T+bq, K=xWk^T+bk, V=xWv^T+bv
// logits = QK^T / sqrt(2048); out = softmax(logits) @ V
//
// R9: K1 (fused QKV) and K2 (scores) moved to the 8-phase 256x256 schedule
// (T2+T3+T4+T5): BK=64, 512 thr = 8 waves (2x4), 128 KiB LDS double-buffered
// in half-tiles, one half-tile staged per phase via global_load_lds, counted
// s_waitcnt vmcnt(4) once per K-tile (never 0 mid-loop), raw s_barrier pairs,
// setprio(1) around each 16-MFMA quadrant cluster. XOR chunk swizzle kept
// (0 bank conflicts). K3 (PV) keeps the proven 128x128 2-phase kernel: a
// 256^2 tile would give only 128 blocks on 256 CUs.
// Liveness: phase p stages into a region whose last reader drained >=2
// barriers earlier; vmcnt(4) leaves only the 2 newest stages (t+2 A0/B0)
// outstanding, so K-tile t+1 is fully landed before its first ds_read.

typedef unsigned short u16;
typedef unsigned int u32;
typedef __bf16 bf16x8 __attribute__((ext_vector_type(8)));
typedef float floatx4 __attribute__((ext_vector_type(4)));

__device__ __forceinline__ u16 f2bf(float f) {
    u32 u = __float_as_uint(f);
    u += 0x7fffu + ((u >> 16) & 1u);   // RNE
    return (u16)(u >> 16);
}

__device__ __forceinline__ void g2lds16(const void* g, void* l) {
    __builtin_amdgcn_global_load_lds(
        (const __attribute__((address_space(1))) unsigned int*)g,
        (__attribute__((address_space(3))) unsigned int*)l,
        16, 0, 0);
}

// ---- fused cast: x -> xb, Wq|Wk|Wv -> wall (3072x1024), zero rowsum ----
__global__ __launch_bounds__(256)
void cvt_all(const float* __restrict__ x, const float* __restrict__ Wq,
             const float* __restrict__ Wk, const float* __restrict__ Wv,
             u16* __restrict__ xb, u16* __restrict__ wall,
             float* __restrict__ rowsum)
{
    const int NX = 2097152;   // B*S*D/4
    const int NW = 262144;    // D*D/4
    const int TOT = NX + 3 * NW;    // 2883584 = 11264 * 256
    int i = blockIdx.x * 256 + threadIdx.x;
    if (i >= TOT) {
        int z = i - TOT;              // 0..2047 -> 8192 floats of rowsum
        float4 zz = {0.f, 0.f, 0.f, 0.f};
        ((float4*)rowsum)[z] = zz;
        return;
    }
    const float* src;
    u16* dst;
    int idx;
    if (i < NX) { src = x; dst = xb; idx = i; }
    else {
        int j = i - NX;
        dst = wall; idx = j;
        src = (j < NW) ? Wq : (j < 2 * NW) ? Wk : Wv;
        int jj = (j < NW) ? j : (j < 2 * NW) ? (j - NW) : (j - 2 * NW);
        float4 v = ((const float4*)src)[jj];
        ushort4 o;
        o.x = f2bf(v.x); o.y = f2bf(v.y); o.z = f2bf(v.z); o.w = f2bf(v.w);
        ((ushort4*)dst)[idx] = o;
        return;
    }
    float4 v = ((const float4*)src)[idx];
    ushort4 o;
    o.x = f2bf(v.x); o.y = f2bf(v.y); o.z = f2bf(v.z); o.w = f2bf(v.w);
    ((ushort4*)dst)[idx] = o;
}

// --------------- old 128x128 2-phase GEMM (kept for K3 / MODE 5) ----------
template<int MODE>
__global__ __launch_bounds__(256)
void gemm_bt(const u16* __restrict__ A, const u16* __restrict__ B,
             void* __restrict__ Out, const float* __restrict__ bias,
             float scale, int M, int N, int K,
             long long sAz, long long sBz, long long sOz,
             void* __restrict__ Out2, void* __restrict__ Out3,
             const float* __restrict__ bias2, const float* __restrict__ bias3,
             float* __restrict__ rowsum)
{
    __shared__ u16 ldsA[2][128 * 64];   // 2 x 16 KB
    __shared__ u16 ldsB[2][128 * 64];   // 2 x 16 KB

    const int tid   = threadIdx.x;
    const int lane  = tid & 63;
    const int wv    = tid >> 6;          // wave 0..3
    const int wm    = (wv >> 1) * 64;
    const int wn    = (wv & 1) * 64;
    const int lhalf = lane & 15;
    const int quad  = lane >> 4;

    const size_t bz = blockIdx.z;
    A += bz * (size_t)sAz;
    B += bz * (size_t)sBz;

    int tm, tn;
    {
        const int ntn = gridDim.x, ntm = gridDim.y;
        const int lin = blockIdx.y * ntn + blockIdx.x;
        const int GM = 4;
        const int width = GM * ntn;
        const int group = lin / width;
        const int first = group * GM;
        const int gsz   = (ntm - first) < GM ? (ntm - first) : GM;
        const int rem   = lin - group * width;
        tm = first + rem % gsz;
        tn = rem / gsz;
    }
    const int m0 = tm * 128;
    const int n0 = tn * 128;

    const int r8 = lane >> 3;
    const int gc = (lane & 7) ^ r8;
    const u16* pa = A + (size_t)(m0 + wv * 32 + r8) * K + gc * 8;
    const u16* pb = B + (size_t)(n0 + wv * 32 + r8) * K + gc * 8;
    const int lofs = wv * 2048;

    floatx4 zero = {0.f, 0.f, 0.f, 0.f};
    floatx4 acc[4][4];
#pragma unroll
    for (int i = 0; i < 4; ++i)
#pragma unroll
        for (int j = 0; j < 4; ++j) acc[i][j] = zero;

    const int swz = lhalf & 7;

#pragma unroll
    for (int j = 0; j < 4; ++j) {
        g2lds16(pa + (size_t)(j * 8) * K, &ldsA[0][lofs + j * 512]);
        g2lds16(pb + (size_t)(j * 8) * K, &ldsB[0][lofs + j * 512]);
    }
    pa += 64; pb += 64;

    int buf = 0;
    for (int k0 = 0; k0 < K; k0 += 64) {
        __syncthreads();
        if (k0 + 64 < K) {
#pragma unroll
            for (int j = 0; j < 4; ++j) {
                g2lds16(pa + (size_t)(j * 8) * K, &ldsA[buf ^ 1][lofs + j * 512]);
                g2lds16(pb + (size_t)(j * 8) * K, &ldsB[buf ^ 1][lofs + j * 512]);
            }
            pa += 64; pb += 64;
        }

        const u16* lA = ldsA[buf];
        const u16* lB = ldsB[buf];
#pragma unroll
        for (int ks = 0; ks < 2; ++ks) {
            const int c = ks * 4 + quad;
            const int p = c ^ swz;
            bf16x8 af[4], bfv[4];
#pragma unroll
            for (int i = 0; i < 4; ++i)
                af[i] = *(const bf16x8*)(lA + (wm + i * 16 + lhalf) * 64 + p * 8);
#pragma unroll
            for (int j = 0; j < 4; ++j)
                bfv[j] = *(const bf16x8*)(lB + (wn + j * 16 + lhalf) * 64 + p * 8);
#pragma unroll
            for (int i = 0; i < 4; ++i)
#pragma unroll
                for (int j = 0; j < 4; ++j)
                    acc[i][j] = __builtin_amdgcn_mfma_f32_16x16x32_bf16(
                        af[i], bfv[j], acc[i][j], 0, 0, 0);
        }
        buf ^= 1;
    }

#pragma unroll
    for (int i = 0; i < 4; ++i) {
        const int mb = m0 + wm + i * 16 + quad * 4;
        if (MODE == 3) {
#pragma unroll
            for (int j = 0; j < 4; ++j) {
                const int n = n0 + wn + j * 16 + lhalf;
                if (n < 1024) {
                    const float bb = bias[n];
#pragma unroll
                    for (int r = 0; r < 4; ++r)
                        ((u16*)Out)[(size_t)(mb + r) * 1024 + n] =
                            f2bf(acc[i][j][r] + bb);
                } else if (n < 2048) {
                    const float bb = bias2[n - 1024];
#pragma unroll
                    for (int r = 0; r < 4; ++r)
                        ((u16*)Out2)[(size_t)(mb + r) * 1024 + (n - 1024)] =
                            f2bf(acc[i][j][r] + bb);
                } else {
                    const int d = n - 2048;
                    const float bb = bias3[d];
                    const int b = mb >> 11;
                    const int s0 = mb & 2047;
                    ushort4 w;
                    w.x = f2bf(acc[i][j][0] + bb);
                    w.y = f2bf(acc[i][j][1] + bb);
                    w.z = f2bf(acc[i][j][2] + bb);
                    w.w = f2bf(acc[i][j][3] + bb);
                    *(ushort4*)((u16*)Out3 + (size_t)b * 2097152 +
                                (size_t)d * 2048 + s0) = w;
                }
            }
        } else if (MODE == 4) {
#pragma unroll
            for (int r = 0; r < 4; ++r) {
                const int m = mb + r;
                float rs = 0.f;
#pragma unroll
                for (int j = 0; j < 4; ++j) {
                    const int n = n0 + wn + j * 16 + lhalf;
                    const float e = __expf(acc[i][j][r] * scale);
                    ((u16*)Out)[bz * (size_t)sOz + (size_t)m * N + n] = f2bf(e);
                    rs += e;
                }
                rs += __shfl_xor(rs, 1, 64);
                rs += __shfl_xor(rs, 2, 64);
                rs += __shfl_xor(rs, 4, 64);
                rs += __shfl_xor(rs, 8, 64);
                if (lhalf == 0)
                    atomicAdd(&rowsum[bz * 2048 + m], rs);
            }
        } else {  // MODE 5: PV with row normalization
            float4 rs4 = *(const float4*)&rowsum[bz * 2048 + mb];
            float rinv[4];
            rinv[0] = __builtin_amdgcn_rcpf(rs4.x);
            rinv[1] = __builtin_amdgcn_rcpf(rs4.y);
            rinv[2] = __builtin_amdgcn_rcpf(rs4.z);
            rinv[3] = __builtin_amdgcn_rcpf(rs4.w);
#pragma unroll
            for (int j = 0; j < 4; ++j) {
                const int n = n0 + wn + j * 16 + lhalf;
#pragma unroll
                for (int r = 0; r < 4; ++r)
                    ((float*)Out)[bz * (size_t)sOz + (size_t)(mb + r) * N + n] =
                        acc[i][j][r] * rinv[r];
            }
        }
    }
}

// --------------- 8-phase 256x256 GEMM (K1: MODE 3, K2: MODE 4) ------------
// 512 thr = 8 waves (wr 0..1 x wc 0..3); per wave 128x64 out = 2x2 quadrant
// copies of 4x2 16x16 frags. BK=64, 2 ksteps/K-tile. LDS [slot][A/B][half]
// of 128x64 bf16 each = 128 KiB. One half-tile (2 x global_load_lds of
// 64 rows x 128 B) staged per phase; per-K-tile schedule:
//   ph1: read A-h0+B-h0 (12 ds_read), stage A-h1(t+1);  MFMA q(0,0)
//   ph2: read B-h1 (4),                stage B-h1(t+1);  MFMA q(0,1)
//   ph3: read A-h1 (8),                stage A-h0(t+2);  MFMA q(1,0)
//   ph4: (regs only),                  stage B-h0(t+2);  MFMA q(1,1)
//        vmcnt(4) [tail: vmcnt(0)]
// Every stage targets a region whose last ds_read drained >=2 barriers ago.
template<int MODE>
__global__ __launch_bounds__(512, 2)
void gemm8p(const u16* __restrict__ A, const u16* __restrict__ B,
            void* __restrict__ Out, const float* __restrict__ bias,
            float scale, int M, int N, int K,
            long long sAz, long long sBz, long long sOz,
            void* __restrict__ Out2, void* __restrict__ Out3,
            const float* __restrict__ bias2, const float* __restrict__ bias3,
            float* __restrict__ rowsum)
{
    __shared__ u16 lds[2][2][2][8192];   // [slot][opA0/B1][half][128*64] = 128 KiB

    const int tid   = threadIdx.x;
    const int lane  = tid & 63;
    const int wv    = tid >> 6;          // 0..7
    const int wr    = wv >> 2;           // wave row 0..1
    const int wc    = wv & 3;            // wave col 0..3
    const int lhalf = lane & 15;
    const int quad  = lane >> 4;
    const int swz   = lhalf & 7;

    const size_t bz = blockIdx.z;
    A += bz * (size_t)sAz;
    B += bz * (size_t)sBz;

    // supertile mapping (GROUP_M=4) for L2 tile reuse
    int tm, tn;
    {
        const int ntn = gridDim.x, ntm = gridDim.y;
        const int lin = blockIdx.y * ntn + blockIdx.x;
        const int GM = 4;
        const int width = GM * ntn;
        const int group = lin / width;
        const int first = group * GM;
        const int gsz   = (ntm - first) < GM ? (ntm - first) : GM;
        const int rem   = lin - group * width;
        tm = first + rem % gsz;
        tn = rem / gsz;
    }
    const int m0 = tm * 256;
    const int n0 = tn * 256;

    // staging: wave wv covers rows (half*128 + issue*64 + wv*8 + lane>>3),
    // src chunk (lane&7)^(lane>>3), stored at phys chunk lane&7 (XOR swz)
    const int r8l = lane >> 3;
    const int gc  = (lane & 7) ^ r8l;
    const u16* pA = A + (size_t)(m0 + wv * 8 + r8l) * K + gc * 8;
    const u16* pB = B + (size_t)(n0 + wv * 8 + r8l) * K + gc * 8;
    const int wofs = wv * 512;           // wave's 8-row strip within 64-row issue

    const int NT = K >> 6;

#define STAGE8(op, slot, half, kt) do {                                        \
    const u16* _s = ((op) ? pB : pA) + (size_t)((half) * 128) * K              \
                    + (size_t)(kt) * 64;                                       \
    u16* _d = &lds[slot][op][half][wofs];                                      \
    g2lds16(_s, _d);                                                           \
    g2lds16(_s + (size_t)64 * K, _d + 4096);                                   \
} while (0)

    bf16x8 af[2][4];        // A frags of current qm: [kstep][i]
    bf16x8 bfr[2][2][2];    // B frags: [qn][kstep][j]
    floatx4 zero = {0.f, 0.f, 0.f, 0.f};
    floatx4 acc[2][2][4][2];
#pragma unroll
    for (int a = 0; a < 2; ++a)
#pragma unroll
    for (int b = 0; b < 2; ++b)
#pragma unroll
    for (int i = 0; i < 4; ++i)
#pragma unroll
    for (int j = 0; j < 2; ++j) acc[a][b][i][j] = zero;

#define LDA8(slot, qm) do {                                                    \
    const u16* _a = &lds[slot][0][qm][0];                                      \
    _Pragma("unroll")                                                          \
    for (int ks = 0; ks < 2; ++ks) {                                           \
        const int p8 = ((ks * 4 + quad) ^ swz) * 8;                            \
        _Pragma("unroll")                                                      \
        for (int i = 0; i < 4; ++i)                                            \
            af[ks][i] = *(const bf16x8*)(_a + (wr * 64 + i * 16 + lhalf) * 64  \
                                         + p8);                                \
    }                                                                          \
} while (0)

#define LDB8(slot, qn) do {                                                    \
    const u16* _b = &lds[slot][1][qn][0];                                      \
    _Pragma("unroll")                                                          \
    for (int ks = 0; ks < 2; ++ks) {                                           \
        const int p8 = ((ks * 4 + quad) ^ swz) * 8;                            \
        _Pragma("unroll")                                                      \
        for (int j = 0; j < 2; ++j)                                            \
            bfr[qn][ks][j] = *(const bf16x8*)(_b +                             \
                (wc * 32 + j * 16 + lhalf) * 64 + p8);                         \
    }                                                                          \
} while (0)

#define MFMAQ(qm, qn) do {                                                     \
    _Pragma("unroll")                                                          \
    for (int ks = 0; ks < 2; ++ks)                                             \
        _Pragma("unroll")                                                      \
        for (int i = 0; i < 4; ++i)                                            \
            _Pragma("unroll")                                                  \
            for (int j = 0; j < 2; ++j)                                        \
                acc[qm][qn][i][j] = __builtin_amdgcn_mfma_f32_16x16x32_bf16(   \
                    af[ks][i], bfr[qn][ks][j], acc[qm][qn][i][j], 0, 0, 0);    \
} while (0)

    // prologue: K-tile 0 complete + K-tile 1 A-h0/B-h0 (6 half-tiles)
    STAGE8(0, 0, 0, 0);
    STAGE8(1, 0, 0, 0);
    STAGE8(0, 0, 1, 0);
    STAGE8(1, 0, 1, 0);
    if (NT > 1) {
        STAGE8(0, 1, 0, 1);
        STAGE8(1, 1, 0, 1);
    }
    asm volatile("s_waitcnt vmcnt(4)");
    __builtin_amdgcn_s_barrier();

    for (int t = 0; t < NT; ++t) {
        const int s = t & 1;
        const bool p1 = (t + 1 < NT), p2 = (t + 2 < NT);

        // ---- phase 1: q(0,0) ----
        LDA8(s, 0);
        LDB8(s, 0);
        if (p1) STAGE8(0, s ^ 1, 1, t + 1);
        __builtin_amdgcn_s_barrier();
        asm volatile("s_waitcnt lgkmcnt(0)");
        __builtin_amdgcn_s_setprio(1);
        MFMAQ(0, 0);
        __builtin_amdgcn_s_setprio(0);
        __builtin_amdgcn_s_barrier();

        // ---- phase 2: q(0,1) ----
        LDB8(s, 1);
        if (p1) STAGE8(1, s ^ 1, 1, t + 1);
        __builtin_amdgcn_s_barrier();
        asm volatile("s_waitcnt lgkmcnt(0)");
        __builtin_amdgcn_s_setprio(1);
        MFMAQ(0, 1);
        __builtin_amdgcn_s_setprio(0);
        __builtin_amdgcn_s_barrier();

        // ---- phase 3: q(1,0) ----
        LDA8(s, 1);
        if (p2) STAGE8(0, s, 0, t + 2);
        __builtin_amdgcn_s_barrier();
        asm volatile("s_waitcnt lgkmcnt(0)");
        __builtin_amdgcn_s_setprio(1);
        MFMAQ(1, 0);
        __builtin_amdgcn_s_setprio(0);
        __builtin_amdgcn_s_barrier();

        // ---- phase 4: q(1,1) ----
        if (p2) STAGE8(1, s, 0, t + 2);
        __builtin_amdgcn_s_barrier();
        asm volatile("s_waitcnt lgkmcnt(0)");
        __builtin_amdgcn_s_setprio(1);
        MFMAQ(1, 1);
        __builtin_amdgcn_s_setprio(0);
        if (p2) asm volatile("s_waitcnt vmcnt(4)");
        else    asm volatile("s_waitcnt vmcnt(0)");
        __builtin_amdgcn_s_barrier();
    }

#undef STAGE8
#undef LDA8
#undef LDB8
#undef MFMAQ

    // epilogue: m = m0 + qm*128 + wr*64 + i*16 + quad*4 + r
    //           n = n0 + qn*128 + wc*32 + j*16 + lhalf
#pragma unroll
    for (int qm = 0; qm < 2; ++qm)
#pragma unroll
    for (int i = 0; i < 4; ++i) {
        const int mb = m0 + qm * 128 + wr * 64 + i * 16 + quad * 4;
        if (MODE == 3) {   // fused QKV (branch uniform per n-frag)
#pragma unroll
            for (int qn = 0; qn < 2; ++qn)
#pragma unroll
            for (int j = 0; j < 2; ++j) {
                const int n = n0 + qn * 128 + wc * 32 + j * 16 + lhalf;
                const floatx4 a = acc[qm][qn][i][j];
                if (n < 1024) {
                    const float bb = bias[n];
#pragma unroll
                    for (int r = 0; r < 4; ++r)
                        ((u16*)Out)[(size_t)(mb + r) * 1024 + n] =
                            f2bf(a[r] + bb);
                } else if (n < 2048) {
                    const float bb = bias2[n - 1024];
#pragma unroll
                    for (int r = 0; r < 4; ++r)
                        ((u16*)Out2)[(size_t)(mb + r) * 1024 + (n - 1024)] =
                            f2bf(a[r] + bb);
                } else {
                    const int d = n - 2048;
                    const float bb = bias3[d];
                    const int b = mb >> 11;     // 4 consecutive m same batch
                    const int s0 = mb & 2047;
                    ushort4 w;
                    w.x = f2bf(a[0] + bb);
                    w.y = f2bf(a[1] + bb);
                    w.z = f2bf(a[2] + bb);
                    w.w = f2bf(a[3] + bb);
                    *(ushort4*)((u16*)Out3 + (size_t)b * 2097152 +
                                (size_t)d * 2048 + s0) = w;
                }
            }
        } else {   // MODE 4: scores: exp + rowsum atomics
#pragma unroll
            for (int r = 0; r < 4; ++r) {
                const int m = mb + r;
                float rs = 0.f;
#pragma unroll
                for (int qn = 0; qn < 2; ++qn)
#pragma unroll
                for (int j = 0; j < 2; ++j) {
                    const int n = n0 + qn * 128 + wc * 32 + j * 16 + lhalf;
                    const float e = __expf(acc[qm][qn][i][j][r] * scale);
                    ((u16*)Out)[bz * (size_t)sOz + (size_t)m * N + n] = f2bf(e);
                    rs += e;
                }
                rs += __shfl_xor(rs, 1, 64);
                rs += __shfl_xor(rs, 2, 64);
                rs += __shfl_xor(rs, 4, 64);
                rs += __shfl_xor(rs, 8, 64);
                if (lhalf == 0)
                    atomicAdd(&rowsum[bz * 2048 + m], rs);
            }
        }
    }
}

extern "C" void kernel_launch(void* const* d_in, const int* in_sizes, int n_in,
                              void* d_out, int out_size, void* d_ws, size_t ws_size,
                              hipStream_t stream)
{
    const float* x  = (const float*)d_in[0];
    const float* Wq = (const float*)d_in[1];
    const float* bq = (const float*)d_in[2];
    const float* Wk = (const float*)d_in[3];
    const float* bk = (const float*)d_in[4];
    const float* Wv = (const float*)d_in[5];
    const float* bv = (const float*)d_in[6];
    float* out = (float*)d_out;

    const int B = 4, S = 2048, D = 1024;
    const long long SD = (long long)S * D;       // 2097152
    const long long SS = (long long)S * S;       // 4194304
    const long long BSD = (long long)B * SD;     // 8388608
    const long long DD = (long long)D * D;       // 1048576

    // workspace layout (bf16 = u16), total ~107 MB
    u16* xb   = (u16*)d_ws;
    u16* wall = xb   + BSD;      // [Wq;Wk;Wv] 3072 x 1024
    u16* Qb   = wall + 3 * DD;
    u16* Kb   = Qb   + BSD;
    u16* Vt   = Kb   + BSD;      // per-batch transposed: Vt[b][d][s]
    u16* Sc   = Vt   + BSD;      // exp(logits) bf16: [b][q][k]
    float* rowsum = (float*)(Sc + B * SS);   // 8192 floats

    // K0: fused casts (x + 3 weights) + rowsum zero-init
    cvt_all<<<dim3(11272), 256, 0, stream>>>(x, Wq, Wk, Wv, xb, wall, rowsum);

    // K1: fused QKV projection (8-phase 256^2): A=xb (8192x1024), B=wall (3072x1024)
    gemm8p<3><<<dim3(3 * D / 256, (B * S) / 256, 1), 512, 0, stream>>>(
        xb, wall, Qb, bq, 1.f, B * S, 3 * D, D, 0, 0, 0,
        Kb, Vt, bk, bv, nullptr);

    // K2: ScE = exp(Q K^T / sqrt(S)) (8-phase 256^2), rowsum += partials
    const float sc = 0.022097086912079608f;  // 1/sqrt(2048)
    gemm8p<4><<<dim3(S / 256, S / 256, B), 512, 0, stream>>>(
        Qb, Kb, Sc, nullptr, sc, S, S, D, SD, SD, SS,
        nullptr, nullptr, nullptr, nullptr, rowsum);

    // K3: out = (ScE @ V) / rowsum   (A = ScE, B = Vt, K = S) — 128^2 kernel
    gemm_bt<5><<<dim3(D / 128, S / 128, B), 256, 0, stream>>>(
        Sc, Vt, out, nullptr, 1.f, S, D, S, SS, SD, SD,
        nullptr, nullptr, nullptr, nullptr, rowsum);
}